// Round 8
// baseline (710.495 us; speedup 1.0000x reference)
//
#include <hip/hip_runtime.h>
#include <hip/hip_bf16.h>
#include <math.h>

#define NN 50000
#define NE 800000
#define FF 64
#define ZD 192

typedef __attribute__((ext_vector_type(8))) short bf16x8;
typedef __attribute__((ext_vector_type(4))) float f32x4;

__device__ __forceinline__ short f2bs(float f){
  union { __hip_bfloat16 h; short s; } u; u.h = __float2bfloat16(f); return u.s;
}
__device__ __forceinline__ unsigned packbf(float a, float b){
  return ((unsigned)(unsigned short)f2bs(b) << 16) | (unsigned)(unsigned short)f2bs(a);
}
__device__ __forceinline__ float lo16f(unsigned u){ union{unsigned u; float f;} v; v.u = u << 16; return v.f; }
__device__ __forceinline__ float hi16f(unsigned u){ union{unsigned u; float f;} v; v.u = u & 0xFFFF0000u; return v.f; }
__device__ __forceinline__ float sigm(float x){ return 1.0f/(1.0f+__expf(-x)); }
__device__ __forceinline__ float sofp(float x){ return fmaxf(x,0.0f)+__logf(1.0f+__expf(-fabsf(x))); }
__device__ __forceinline__ float fsilu(float x){ return x/(1.0f+__expf(-x)); }

// ---------------------------------------------------------------------------
// CSR build (by dst).  Slot order nondeterministic -> f32 sum-order noise only.
// ---------------------------------------------------------------------------
__global__ __launch_bounds__(256) void kz(int* __restrict__ cnt){
  int i = blockIdx.x*256 + threadIdx.x;
  if (i < NN) cnt[i] = 0;
}
__global__ __launch_bounds__(256) void kh(const int* __restrict__ eidx, int* __restrict__ cnt){
  int e = blockIdx.x*256 + threadIdx.x;
  if (e < NE) atomicAdd(&cnt[eidx[NE + e]], 1);
}
#define SCHUNK 49
__global__ __launch_bounds__(1024) void kscan(const int* __restrict__ cnt,
                                              int* __restrict__ off, int* __restrict__ cur){
  __shared__ int bs[1024];
  int t = threadIdx.x;
  int base = t * SCHUNK;
  int s = 0;
  for (int i = 0; i < SCHUNK; i++){ int idx = base + i; if (idx < NN) s += cnt[idx]; }
  bs[t] = s;
  for (int d = 1; d < 1024; d <<= 1){
    __syncthreads();
    int u = (t >= d) ? bs[t-d] : 0;
    __syncthreads();
    bs[t] += u;
  }
  __syncthreads();
  int run = bs[t] - s;
  for (int i = 0; i < SCHUNK; i++){
    int idx = base + i;
    if (idx < NN){ off[idx] = run; cur[idx] = run; run += cnt[idx]; }
  }
  if (t == 0) off[NN] = bs[1023];
}
__global__ __launch_bounds__(256) void kscat(const int* __restrict__ eidx,
                                             int* __restrict__ cur, int* __restrict__ csr){
  int e = blockIdx.x*256 + threadIdx.x;
  if (e < NE){ int slot = atomicAdd(&cur[eidx[NE + e]], 1); csr[slot] = e; }
}

// ---------------------------------------------------------------------------
// k1: per-node gating-linear parts via MFMA (packed bf16 pairs).
//  P2u[n*128 + o] = pack(Af,As) ; P2u[n*128+64+o] = pack(Bf,Bs)
//  copy_aout!=0: also aout=atom (fallback path only).
// ---------------------------------------------------------------------------
__global__ __launch_bounds__(256) void k1_node_pre(
    const float* __restrict__ atom,
    const float* __restrict__ wf, const float* __restrict__ ws,
    unsigned* __restrict__ P2u, float* __restrict__ aout, int copy_aout)
{
  if (copy_aout) {
    int tid0 = blockIdx.x * 256 + threadIdx.x;
    int nthr = gridDim.x * 256;
    const float4* a4 = (const float4*)atom;
    float4* o4 = (float4*)aout;
    for (int i = tid0; i < NN*FF/4; i += nthr) o4[i] = a4[i];
  }
  int lane = threadIdx.x & 63;
  int c = lane & 15, kb = lane >> 4;
  int wid = blockIdx.x * 4 + (threadIdx.x >> 6);
  int nw = gridDim.x * 4;
  for (int g = wid; g < NN/16; g += nw) {
    int n0 = g * 16;
    const float* arow = &atom[(size_t)(n0 + c) * FF + kb*8];
    bf16x8 A0, A1;
    #pragma unroll
    for (int j = 0; j < 8; j++) { A0[j] = f2bs(arow[j]); A1[j] = f2bs(arow[32+j]); }
    f32x4 acc[16];
    #pragma unroll
    for (int t = 0; t < 16; t++) acc[t] = (f32x4){0,0,0,0};
    #pragma unroll
    for (int t = 0; t < 16; t++) {
      int og = t*16 + c;
      const float* src;
      if (t < 4)       src = &wf[og*ZD];
      else if (t < 8)  src = &wf[(og-64)*ZD + 64];
      else if (t < 12) src = &ws[(og-128)*ZD];
      else             src = &ws[(og-192)*ZD + 64];
      bf16x8 B0, B1;
      #pragma unroll
      for (int j = 0; j < 8; j++) { B0[j] = f2bs(src[kb*8+j]); B1[j] = f2bs(src[32+kb*8+j]); }
      acc[t] = __builtin_amdgcn_mfma_f32_16x16x32_bf16(A0, B0, acc[t], 0,0,0);
      acc[t] = __builtin_amdgcn_mfma_f32_16x16x32_bf16(A1, B1, acc[t], 0,0,0);
    }
    #pragma unroll
    for (int t = 0; t < 8; t++) {
      #pragma unroll
      for (int r = 0; r < 4; r++) {
        int n = n0 + kb*4 + r;
        P2u[(size_t)n*128 + t*16 + c] = packbf(acc[t][r], acc[t+8][r]);
      }
    }
  }
}

// ---------------------------------------------------------------------------
// k2a: pure streaming edge GEMM.  16 edges/wave; 9 tiles (zf 0-3, zs 4-7,
// fc1-edge 8).  Writes Zpk (zf,zs packed bf16, no bias) + fc1 stash to eout.
// No gathers, no atomics, no shuffles.
// ---------------------------------------------------------------------------
__global__ __launch_bounds__(256) void k2a_gemm(
    const float* __restrict__ efea,
    const float* __restrict__ wf, const float* __restrict__ ws,
    const float* __restrict__ fc1w,
    unsigned* __restrict__ Zpk, float* __restrict__ eout)
{
  int tid = threadIdx.x;
  int lane = tid & 63;
  int lw = tid >> 6;
  int c = lane & 15, kb = lane >> 4;

  bf16x8 Bf[9][2];
  #pragma unroll
  for (int t = 0; t < 9; t++) {
    int og = t*16 + c;
    const float* src = nullptr;
    if (t < 4)            src = &wf[og*ZD + 128];
    else if (t < 8)       src = &ws[(og-64)*ZD + 128];
    else if (og-128 < 14) src = &fc1w[(og-128)*ZD + 128];
    #pragma unroll
    for (int f = 0; f < 2; f++) {
      bf16x8 r;
      #pragma unroll
      for (int j = 0; j < 8; j++) r[j] = src ? f2bs(src[f*32 + kb*8 + j]) : (short)0;
      Bf[t][f] = r;
    }
  }

  int wid = blockIdx.x*4 + lw;
  int nw = gridDim.x*4;
  for (int g = wid; g < NE/16; g += nw) {
    int e0 = g*16;
    const float* erow = &efea[(size_t)(e0 + c)*FF + kb*8];
    bf16x8 A0, A1;
    #pragma unroll
    for (int j = 0; j < 8; j++) { A0[j] = f2bs(erow[j]); A1[j] = f2bs(erow[32+j]); }
    f32x4 acc[9];
    #pragma unroll
    for (int t = 0; t < 9; t++) acc[t] = (f32x4){0,0,0,0};
    #pragma unroll
    for (int t = 0; t < 9; t++) {
      acc[t] = __builtin_amdgcn_mfma_f32_16x16x32_bf16(A0, Bf[t][0], acc[t], 0,0,0);
      acc[t] = __builtin_amdgcn_mfma_f32_16x16x32_bf16(A1, Bf[t][1], acc[t], 0,0,0);
    }
    // D layout: row(=edge)=kb*4+r, col=c
    if (c < 14) {
      #pragma unroll
      for (int r = 0; r < 4; r++)
        eout[(size_t)(e0 + kb*4 + r)*FF + c] = acc[8][r];
    }
    #pragma unroll
    for (int t = 0; t < 4; t++) {
      #pragma unroll
      for (int r = 0; r < 4; r++)
        Zpk[(size_t)(e0 + kb*4 + r)*FF + t*16 + c] = packbf(acc[t][r], acc[t+4][r]);
    }
  }
}

// ---------------------------------------------------------------------------
// k2b: CSR aggregation, one wave per node, NO atomics.
//  Per edge: coalesced 256B Zpk row + 256B P2u src row; gate; accumulate.
//  Depth-4 static-slot software pipeline (no runtime-indexed reg arrays).
// ---------------------------------------------------------------------------
__global__ __launch_bounds__(256) void k2b_agg(
    const int* __restrict__ eidx, const float* __restrict__ dist,
    const float* __restrict__ atom,
    const float* __restrict__ bfb, const float* __restrict__ bsb,
    const int* __restrict__ off, const int* __restrict__ csr,
    const unsigned* __restrict__ P2u, const unsigned* __restrict__ Zpk,
    float* __restrict__ aout)
{
  int lane = threadIdx.x & 63;
  int lw = threadIdx.x >> 6;
  int wid = blockIdx.x*4 + lw;
  int nw = gridDim.x*4;
  float bfo = bfb[lane], bso = bsb[lane];

  for (int n = wid; n < NN; n += nw) {
    int p0 = off[n], p1 = off[n+1];
    unsigned vd = P2u[(size_t)n*128 + lane];
    float Af = lo16f(vd), As = hi16f(vd);
    float sum = 0.f;
    for (int base = p0; base < p1; base += 64) {
      int m = p1 - base; if (m > 64) m = 64;
      // lane-parallel metadata for up to 64 edges
      int lidx = lane < m ? lane : (m-1);
      int ce = csr[base + lidx];
      int se = eidx[ce];
      float de = dist[ce];
      float wde = __expf(-de*de*(1.0f/18.0f));

      unsigned z0,v0,z1,v1,z2,v2,z3,v3;
      #define LOADSLOT(zz, vv, IDX) { int uu=(IDX); if(uu>m-1)uu=m-1; \
        int e_=__shfl(ce,uu,64); int s_=__shfl(se,uu,64); \
        zz=Zpk[(size_t)e_*FF+lane]; vv=P2u[(size_t)s_*128+64+lane]; }
      LOADSLOT(z0,v0,0) LOADSLOT(z1,v1,1) LOADSLOT(z2,v2,2) LOADSLOT(z3,v3,3)
      for (int ub = 0; ub < m; ub += 4) {
        unsigned cz0=z0,cv0=v0,cz1=z1,cv1=v1,cz2=z2,cv2=v2,cz3=z3,cv3=v3;
        if (ub + 4 < m) {
          LOADSLOT(z0,v0,ub+4) LOADSLOT(z1,v1,ub+5)
          LOADSLOT(z2,v2,ub+6) LOADSLOT(z3,v3,ub+7)
        }
        #define GATE(czz, cvv, IDX) if ((IDX) < m) { \
          float wd_=__shfl(wde,(IDX),64); \
          float zf=lo16f(czz)+Af+lo16f(cvv)+bfo; \
          float zs=hi16f(czz)+As+hi16f(cvv)+bso; \
          sum += sigm(zf)*sofp(zs)*wd_; }
        GATE(cz0,cv0,ub) GATE(cz1,cv1,ub+1) GATE(cz2,cv2,ub+2) GATE(cz3,cv3,ub+3)
        #undef GATE
      }
      #undef LOADSLOT
    }
    aout[(size_t)n*FF + lane] = sum + atom[(size_t)n*FF + lane];
  }
}

// ---------------------------------------------------------------------------
// k2_mono: R5's proven monolith (fallback when ws too small for Zpk).
// ---------------------------------------------------------------------------
__global__ __launch_bounds__(256) void k2_mono(
    const int* __restrict__ eidx, const float* __restrict__ efea,
    const float* __restrict__ dist,
    const float* __restrict__ wf, const float* __restrict__ ws,
    const float* __restrict__ bfb, const float* __restrict__ bsb,
    const float* __restrict__ fc1w,
    const unsigned* __restrict__ P2u, float* __restrict__ aout,
    float* __restrict__ eout)
{
  int tid = threadIdx.x;
  int lane = tid & 63;
  int lw = tid >> 6;
  int c = lane & 15, kb = lane >> 4;
  bf16x8 Bf[9][2];
  #pragma unroll
  for (int t = 0; t < 9; t++) {
    int og = t*16 + c;
    const float* src = nullptr;
    if (t < 4)            src = &wf[og*ZD + 128];
    else if (t < 8)       src = &ws[(og-64)*ZD + 128];
    else if (og-128 < 14) src = &fc1w[(og-128)*ZD + 128];
    #pragma unroll
    for (int f = 0; f < 2; f++) {
      bf16x8 r;
      #pragma unroll
      for (int j = 0; j < 8; j++) r[j] = src ? f2bs(src[f*32 + kb*8 + j]) : (short)0;
      Bf[t][f] = r;
    }
  }
  float bfo[4], bso[4];
  #pragma unroll
  for (int t = 0; t < 4; t++) { bfo[t] = bfb[t*16+c]; bso[t] = bsb[t*16+c]; }
  int wid = blockIdx.x*4 + lw;
  int nw = gridDim.x*4;
  for (int g = wid; g < NE/16; g += nw) {
    int e0 = g*16;
    int   sNv = eidx[e0 + (lane & 15)];
    int   dNv = eidx[NE + e0 + (lane & 15)];
    float dev = dist[e0 + (lane & 15)];
    float wdv = __expf(-dev*dev*(1.0f/18.0f));
    const float* erow = &efea[(size_t)(e0 + c)*FF + kb*8];
    bf16x8 A0, A1;
    #pragma unroll
    for (int j = 0; j < 8; j++) { A0[j] = f2bs(erow[j]); A1[j] = f2bs(erow[32+j]); }
    f32x4 acc[9];
    #pragma unroll
    for (int t = 0; t < 9; t++) acc[t] = (f32x4){0,0,0,0};
    #pragma unroll
    for (int t = 0; t < 9; t++) {
      acc[t] = __builtin_amdgcn_mfma_f32_16x16x32_bf16(A0, Bf[t][0], acc[t], 0,0,0);
      acc[t] = __builtin_amdgcn_mfma_f32_16x16x32_bf16(A1, Bf[t][1], acc[t], 0,0,0);
    }
    if (c < 14) {
      #pragma unroll
      for (int r = 0; r < 4; r++)
        eout[(size_t)(e0 + kb*4 + r)*FF + c] = acc[8][r];
    }
    int sN[4], dN[4]; float wd[4];
    #pragma unroll
    for (int r = 0; r < 4; r++) {
      sN[r] = __shfl(sNv, kb*4 + r, 64);
      dN[r] = __shfl(dNv, kb*4 + r, 64);
      wd[r] = __shfl(wdv, kb*4 + r, 64);
    }
    unsigned vdu[4][4], vsu[4][4];
    #pragma unroll
    for (int r = 0; r < 4; r++) {
      #pragma unroll
      for (int t = 0; t < 4; t++) {
        vdu[r][t] = P2u[(size_t)dN[r]*128 + t*16 + c];
        vsu[r][t] = P2u[(size_t)sN[r]*128 + 64 + t*16 + c];
      }
    }
    #pragma unroll
    for (int r = 0; r < 4; r++) {
      #pragma unroll
      for (int t = 0; t < 4; t++) {
        float zf = acc[t][r]   + lo16f(vdu[r][t]) + lo16f(vsu[r][t]) + bfo[t];
        float zs = acc[t+4][r] + hi16f(vdu[r][t]) + hi16f(vsu[r][t]) + bso[t];
        float m = sigm(zf) * sofp(zs) * wd[r];
        atomicAdd(&aout[(size_t)dN[r]*FF + t*16 + c], m);
      }
    }
  }
}

// ---------------------------------------------------------------------------
// k3: per-node fc1 partials on UPDATED node features.
// ---------------------------------------------------------------------------
__global__ __launch_bounds__(256) void k3_cpre(
    const float* __restrict__ aout, const float* __restrict__ fc1w,
    float* __restrict__ C)
{
  __shared__ float wT[64*32];
  __shared__ float xs[4][64];
  int tid = threadIdx.x;
  for (int i = tid; i < 64*28; i += 256) {
    int k = i / 28, j = i % 28;
    wT[k*32 + j] = (j < 14) ? fc1w[j*ZD + k] : fc1w[(j-14)*ZD + 64 + k];
  }
  __syncthreads();
  int o  = tid & 63;
  int lw = tid >> 6;
  int wid = blockIdx.x * 4 + lw;
  int nw  = gridDim.x * 4;
  for (int n = wid; n < NN; n += nw) {
    xs[lw][o] = aout[(size_t)n*FF + o];
    float acc = 0.f;
    if (o < 28) {
      for (int k = 0; k < 64; k++) acc += xs[lw][k] * wT[k*32 + o];
      C[n*28 + o] = acc;
    }
  }
}

// ---------------------------------------------------------------------------
// k5: edge-update MLP. 8 edges/wave. h-edge-part read from eout stash.
// ---------------------------------------------------------------------------
__global__ __launch_bounds__(256) void k5_edge_mlp(
    const int* __restrict__ eidx,
    const float* __restrict__ fc1b,
    const float* __restrict__ fc2w, const float* __restrict__ fc2b,
    const float* __restrict__ C, float* __restrict__ eout)
{
  __shared__ float w2T[14*64];
  __shared__ float hs[4][128];
  int tid = threadIdx.x;
  for (int i = tid; i < 14*64; i += 256) {
    int j = i >> 6, o = i & 63;
    w2T[i] = fc2w[o*14 + j];
  }
  __syncthreads();
  int o  = tid & 63;
  int lw = tid >> 6;
  int j4 = o >> 2, q = o & 3;
  int wid = blockIdx.x*4 + lw;
  int nw  = gridDim.x*4;
  for (int g = wid; g < NE/8; g += nw) {
    int e0 = g*8;
    #pragma unroll
    for (int pass = 0; pass < 2; pass++) {
      int ee = pass*4 + q;
      int e = e0 + ee;
      if (j4 < 14) {
        int sN = eidx[e], dN = eidx[NE+e];
        float h = eout[(size_t)e*FF + j4] + C[sN*28 + j4] + C[dN*28 + 14 + j4] + fc1b[j4];
        hs[lw][ee*16 + j4] = fsilu(h);
      }
    }
    asm volatile("s_waitcnt lgkmcnt(0)" ::: "memory");  // in-wave LDS RAW
    float b2 = fc2b[o];
    #pragma unroll
    for (int ee = 0; ee < 8; ee++) {
      float acc = b2;
      #pragma unroll
      for (int jj = 0; jj < 14; jj++)
        acc += w2T[jj*64 + o] * hs[lw][ee*16 + jj];
      eout[(size_t)(e0 + ee)*FF + o] = fsilu(acc);
    }
  }
}

// ---------------------------------------------------------------------------
extern "C" void kernel_launch(void* const* d_in, const int* in_sizes, int n_in,
                              void* d_out, int out_size, void* d_ws, size_t ws_size,
                              hipStream_t stream) {
  const float* atom  = (const float*)d_in[0];
  const int*   eidx  = (const int*)  d_in[1];
  const float* efea  = (const float*)d_in[2];
  const float* dist  = (const float*)d_in[4];
  const float* wf    = (const float*)d_in[6];
  const float* bf    = (const float*)d_in[7];
  const float* ws    = (const float*)d_in[8];
  const float* bs    = (const float*)d_in[9];
  const float* fc1w  = (const float*)d_in[10];
  const float* fc1b  = (const float*)d_in[11];
  const float* fc2w  = (const float*)d_in[12];
  const float* fc2b  = (const float*)d_in[13];

  float* aout = (float*)d_out;                 // [50000, 64]
  float* eout = aout + (size_t)NN * FF;        // [800000, 64]

  char* wp = (char*)d_ws;
  unsigned* P2u = (unsigned*)wp;  wp += (size_t)NN * 128 * 4;   // 25.6 MB
  float*    C   = (float*)wp;     wp += (size_t)NN * 28 * 4;    //  5.6 MB
  int*      cnt = (int*)wp;       wp += (size_t)(NN + 64) * 4;
  int*      off = (int*)wp;       wp += (size_t)(NN + 64) * 4;
  int*      cur = (int*)wp;       wp += (size_t)(NN + 64) * 4;
  int*      csr = (int*)wp;       wp += (size_t)NE * 4;         //  3.2 MB
  unsigned* Zpk = (unsigned*)wp;  wp += (size_t)NE * FF * 4;    // 204.8 MB
  bool split = ((size_t)(wp - (char*)d_ws)) <= ws_size;

  if (split) {
    hipLaunchKernelGGL(kz,    dim3((NN+255)/256), dim3(256), 0, stream, cnt);
    hipLaunchKernelGGL(kh,    dim3((NE+255)/256), dim3(256), 0, stream, eidx, cnt);
    hipLaunchKernelGGL(kscan, dim3(1), dim3(1024), 0, stream, cnt, off, cur);
    hipLaunchKernelGGL(kscat, dim3((NE+255)/256), dim3(256), 0, stream, eidx, cur, csr);
    hipLaunchKernelGGL(k1_node_pre, dim3(512), dim3(256), 0, stream,
                       atom, wf, ws, P2u, aout, 0);
    hipLaunchKernelGGL(k2a_gemm, dim3(2048), dim3(256), 0, stream,
                       efea, wf, ws, fc1w, Zpk, eout);
    hipLaunchKernelGGL(k2b_agg, dim3(4096), dim3(256), 0, stream,
                       eidx, dist, atom, bf, bs, off, csr, P2u, Zpk, aout);
  } else {
    hipLaunchKernelGGL(k1_node_pre, dim3(512), dim3(256), 0, stream,
                       atom, wf, ws, P2u, aout, 1);
    hipLaunchKernelGGL(k2_mono, dim3(1024), dim3(256), 0, stream,
                       eidx, efea, dist, wf, ws, bf, bs, fc1w, P2u, aout, eout);
  }
  hipLaunchKernelGGL(k3_cpre, dim3(512), dim3(256), 0, stream,
                     aout, fc1w, C);
  hipLaunchKernelGGL(k5_edge_mlp, dim3(2048), dim3(256), 0, stream,
                     eidx, fc1b, fc2w, fc2b, C, eout);
}